// Round 8
// baseline (552.573 us; speedup 1.0000x reference)
//
#include <hip/hip_runtime.h>
#include <hip/hip_bf16.h>
#include <cmath>

// Problem constants
#define NN 50000
#define EE 800000
#define ET 850000   // EE + NN self loops
#define HH 4
#define CC1 128
#define CC2 64
#define FIN 256
#define NCLS 50

typedef __attribute__((ext_vector_type(8))) short   short8;
typedef __attribute__((ext_vector_type(8))) unsigned short ushort8;
typedef __attribute__((ext_vector_type(4))) unsigned short ushortx4;
typedef __attribute__((ext_vector_type(4))) float   floatx4;

__device__ __forceinline__ unsigned short f2bf(float f) {
    union { float f; unsigned int u; } x; x.f = f;
    unsigned int lsb = (x.u >> 16) & 1u;
    x.u += 0x7fffu + lsb;          // round-to-nearest-even
    return (unsigned short)(x.u >> 16);
}
__device__ __forceinline__ float bf2f(unsigned short b) {
    union { unsigned int u; float f; } x; x.u = ((unsigned int)b) << 16;
    return x.f;
}

// async global->LDS, 16B per lane, wave-uniform LDS base + lane*16
typedef const __attribute__((address_space(1))) unsigned int* glds_gp_t;
typedef __attribute__((address_space(3))) unsigned int* glds_lp_t;
__device__ __forceinline__ void glds16(const void* g, void* l) {
    __builtin_amdgcn_global_load_lds((glds_gp_t)g, (glds_lp_t)l, 16, 0, 0);
}

// ------------- fused prep: cast x -> bf16, transpose W1/W2, pad Wf ----------
// block-range dispatch, 256 threads each.
#define NB_CAST 12500                  // NN*FIN/4 / 256
#define NB_W1   512                    // 256*512/256
#define NB_W2   512                    // 512*256/256
#define NB_WF   64                     // 256*64/256
__global__ __launch_bounds__(256) void prep_fused(
    const float* __restrict__ x, unsigned short* __restrict__ xb,
    const float* __restrict__ W1, unsigned short* __restrict__ W1t,
    const float* __restrict__ W2, unsigned short* __restrict__ W2t,
    const float* __restrict__ Wf, unsigned short* __restrict__ Wft)
{
    int b = blockIdx.x;
    if (b < NB_CAST) {
        int t = b * 256 + threadIdx.x;          // t < 3.2M
        float4 v = *(const float4*)(x + 4 * (size_t)t);
        unsigned int lo = (unsigned int)f2bf(v.x) | ((unsigned int)f2bf(v.y) << 16);
        unsigned int hi = (unsigned int)f2bf(v.z) | ((unsigned int)f2bf(v.w) << 16);
        *(uint2*)(xb + 4 * (size_t)t) = make_uint2(lo, hi);
    } else if (b < NB_CAST + NB_W1) {
        int t = (b - NB_CAST) * 256 + threadIdx.x;   // K=256, N=512
        int n = t >> 8, k = t & 255;
        W1t[t] = f2bf(W1[(size_t)k * 512 + n]);
    } else if (b < NB_CAST + NB_W1 + NB_W2) {
        int t = (b - NB_CAST - NB_W1) * 256 + threadIdx.x;  // K=512, N=256
        int n = t >> 9, k = t & 511;
        W2t[t] = f2bf(W2[(size_t)k * 256 + n]);
    } else {
        int t = (b - NB_CAST - NB_W1 - NB_W2) * 256 + threadIdx.x;  // K=256, Npad=64
        int n = t >> 8, k = t & 255;
        Wft[t] = (n < NCLS) ? f2bf(Wf[(size_t)k * NCLS + n]) : (unsigned short)0;
    }
}

// ------- bf16 MFMA GEMM + fused attention-score epilogue --------------------
// C[M,N] = A[M,K] @ Bt[N,K]^T, output bf16.
// Epilogue: per row r, head h: atomicAdd asrc[r*4+h] += sum_c C[r,c]*a_src[c]
// (and adst). Each wave's 64 columns lie in ONE head (HSH = log2(C_head)).
template<int HSH>
__global__ __launch_bounds__(256) void gemm_bf16_v3(
    const unsigned short* __restrict__ A,
    const unsigned short* __restrict__ Bt,
    unsigned short* __restrict__ C,
    const float* __restrict__ a_src_full,   // [N] flat (H*C)
    const float* __restrict__ a_dst_full,
    float* __restrict__ asrc,               // [M,H] pre-zeroed
    float* __restrict__ adst,
    int M, int N, int K)
{
    __shared__ unsigned short As[128 * 32];
    __shared__ unsigned short Bs[128 * 32];
    int tid = threadIdx.x, wave = tid >> 6, lane = tid & 63;
    int wm = (wave >> 1) * 64, wn = (wave & 1) * 64;
    int row0 = blockIdx.x * 128, col0 = blockIdx.y * 128;
    int lm = lane & 15, lq = lane >> 4, kq = lq * 8;
    floatx4 acc[4][4] = {};

    int srow = wave * 32 + (lane >> 2);
    int skk  = (lane & 3) * 8;
    int gra0 = row0 + srow;      if (gra0 >= M) gra0 = M - 1;
    int gra1 = row0 + srow + 16; if (gra1 >= M) gra1 = M - 1;
    const unsigned short* ga0 = A + (size_t)gra0 * K + skk;
    const unsigned short* ga1 = A + (size_t)gra1 * K + skk;
    const unsigned short* gb0 = Bt + (size_t)(col0 + srow) * K + skk;
    const unsigned short* gb1 = Bt + (size_t)(col0 + srow + 16) * K + skk;
    unsigned short* la0 = &As[(wave * 32) * 32];
    unsigned short* la1 = &As[(wave * 32 + 16) * 32];
    unsigned short* lb0 = &Bs[(wave * 32) * 32];
    unsigned short* lb1 = &Bs[(wave * 32 + 16) * 32];

    for (int k0 = 0; k0 < K; k0 += 32) {
        __syncthreads();
        glds16(ga0 + k0, la0);
        glds16(ga1 + k0, la1);
        glds16(gb0 + k0, lb0);
        glds16(gb1 + k0, lb1);
        __syncthreads();

        short8 af[4], bfr[4];
        #pragma unroll
        for (int mt = 0; mt < 4; ++mt)
            af[mt] = *(const short8*)&As[(wm + mt * 16 + lm) * 32 + kq];
        #pragma unroll
        for (int nt = 0; nt < 4; ++nt)
            bfr[nt] = *(const short8*)&Bs[(wn + nt * 16 + lm) * 32 + kq];
        #pragma unroll
        for (int mt = 0; mt < 4; ++mt)
            #pragma unroll
            for (int nt = 0; nt < 4; ++nt)
                acc[mt][nt] = __builtin_amdgcn_mfma_f32_16x16x32_bf16(
                    af[mt], bfr[nt], acc[mt][nt], 0, 0, 0);
    }

    // C/D layout: col = lane&15, row = (lane>>4)*4 + reg
    #pragma unroll
    for (int mt = 0; mt < 4; ++mt) {
        int rbase = row0 + wm + mt * 16 + lq * 4;
        #pragma unroll
        for (int nt = 0; nt < 4; ++nt) {
            int c = col0 + wn + nt * 16 + lm;
            #pragma unroll
            for (int r = 0; r < 4; ++r) {
                int gr = rbase + r;
                if (gr < M) C[(size_t)gr * N + c] = f2bf(acc[mt][nt][r]);
            }
        }
    }

    // ---- fused attention-score epilogue ----
    float asw[4], adw[4];
    #pragma unroll
    for (int nt = 0; nt < 4; ++nt) {
        int c = col0 + wn + nt * 16 + lm;
        asw[nt] = a_src_full[c];
        adw[nt] = a_dst_full[c];
    }
    int head = (col0 + wn) >> HSH;    // wave-uniform
    #pragma unroll
    for (int mt = 0; mt < 4; ++mt) {
        #pragma unroll
        for (int r = 0; r < 4; ++r) {
            float s1 = acc[mt][0][r] * asw[0] + acc[mt][1][r] * asw[1]
                     + acc[mt][2][r] * asw[2] + acc[mt][3][r] * asw[3];
            float s2 = acc[mt][0][r] * adw[0] + acc[mt][1][r] * adw[1]
                     + acc[mt][2][r] * adw[2] + acc[mt][3][r] * adw[3];
            #pragma unroll
            for (int o = 1; o < 16; o <<= 1) {
                s1 += __shfl_xor(s1, o, 64);
                s2 += __shfl_xor(s2, o, 64);
            }
            int row = row0 + wm + mt * 16 + lq * 4 + r;
            if (lm == 0 && row < M) {
                atomicAdd(&asrc[row * HH + head], s1);
                atomicAdd(&adst[row * HH + head], s2);
            }
        }
    }
}

// ---- final classifier: out[M,50] f32 = A[M,256]bf16 @ Bt[64,256]^T + bias --
__global__ __launch_bounds__(128) void gemm_final(
    const unsigned short* __restrict__ A,
    const unsigned short* __restrict__ Bt,   // [64,256], rows >= 50 are zero
    const float* __restrict__ bias,
    float* __restrict__ out, int M)
{
    __shared__ unsigned short As[128 * 40];
    __shared__ unsigned short Bs[64 * 40];
    int tid = threadIdx.x, wave = tid >> 6, lane = tid & 63;
    int row0 = blockIdx.x * 128;
    int lm = lane & 15, lq = lane >> 4, kq = lq * 8;
    floatx4 acc[4][4] = {};

    for (int k0 = 0; k0 < 256; k0 += 32) {
        int gr = row0 + tid; if (gr >= M) gr = M - 1;
        const unsigned short* ap = A + (size_t)gr * 256 + k0;
        ushort8 a0 = *(const ushort8*)ap;
        ushort8 a1 = *(const ushort8*)(ap + 8);
        ushort8 a2 = *(const ushort8*)(ap + 16);
        ushort8 a3 = *(const ushort8*)(ap + 24);
        const unsigned short* bp = Bt + (size_t)(tid >> 1) * 256 + k0 + (tid & 1) * 16;
        ushort8 b0 = *(const ushort8*)bp;
        ushort8 b1 = *(const ushort8*)(bp + 8);
        __syncthreads();
        *(ushort8*)&As[tid * 40 + 0]  = a0;
        *(ushort8*)&As[tid * 40 + 8]  = a1;
        *(ushort8*)&As[tid * 40 + 16] = a2;
        *(ushort8*)&As[tid * 40 + 24] = a3;
        *(ushort8*)&Bs[(tid >> 1) * 40 + (tid & 1) * 16]     = b0;
        *(ushort8*)&Bs[(tid >> 1) * 40 + (tid & 1) * 16 + 8] = b1;
        __syncthreads();

        short8 af[4], bfr[4];
        #pragma unroll
        for (int mt = 0; mt < 4; ++mt)
            af[mt] = *(const short8*)&As[(wave * 64 + mt * 16 + lm) * 40 + kq];
        #pragma unroll
        for (int nt = 0; nt < 4; ++nt)
            bfr[nt] = *(const short8*)&Bs[(nt * 16 + lm) * 40 + kq];
        #pragma unroll
        for (int mt = 0; mt < 4; ++mt)
            #pragma unroll
            for (int nt = 0; nt < 4; ++nt)
                acc[mt][nt] = __builtin_amdgcn_mfma_f32_16x16x32_bf16(
                    af[mt], bfr[nt], acc[mt][nt], 0, 0, 0);
    }

    #pragma unroll
    for (int mt = 0; mt < 4; ++mt) {
        int rbase = row0 + wave * 64 + mt * 16 + lq * 4;
        #pragma unroll
        for (int nt = 0; nt < 4; ++nt) {
            int c = nt * 16 + lm;
            if (c >= NCLS) continue;
            float bv = bias[c];
            #pragma unroll
            for (int r = 0; r < 4; ++r) {
                int gr = rbase + r;
                if (gr < M) out[(size_t)gr * NCLS + c] = acc[mt][nt][r] + bv;
            }
        }
    }
}

// ---------------- CSR build: histogram, hierarchical scan, scatter ----------
__global__ void edge_histogram(const int* __restrict__ ei, int* __restrict__ deg)
{
    int t = blockIdx.x * blockDim.x + threadIdx.x;
    if (t >= ET) return;
    int dst = (t < EE) ? ei[EE + t] : (t - EE);
    atomicAdd(&deg[dst], 1);
}

// phase 1: partials[b] = sum(deg[b*2048 .. b*2048+2047])
__global__ __launch_bounds__(256) void scan_reduce(
    const int* __restrict__ deg, int* __restrict__ partials)
{
    int i0 = blockIdx.x * 2048 + threadIdx.x * 8;
    int s = 0;
    #pragma unroll
    for (int k = 0; k < 8; ++k) { int i = i0 + k; s += (i < NN) ? deg[i] : 0; }
    #pragma unroll
    for (int o = 32; o > 0; o >>= 1) s += __shfl_xor(s, o, 64);
    __shared__ int ws[4];
    int lane = threadIdx.x & 63, wid = threadIdx.x >> 6;
    if (lane == 0) ws[wid] = s;
    __syncthreads();
    if (threadIdx.x == 0) partials[blockIdx.x] = ws[0] + ws[1] + ws[2] + ws[3];
}

// phase 2: per-chunk scan + base (partials scanned redundantly per block)
#define SCAN_NB 25                      // ceil(50000/2048)
__global__ __launch_bounds__(256) void scan_apply(
    const int* __restrict__ deg, const int* __restrict__ partials,
    int* __restrict__ off, int* __restrict__ pos)
{
    __shared__ int spE[SCAN_NB];
    __shared__ int ws[4];
    int lane = threadIdx.x & 63, wid = threadIdx.x >> 6;
    if (wid == 0) {                     // wave 0: exclusive scan of partials
        int v = (lane < SCAN_NB) ? partials[lane] : 0;
        int s = v;
        #pragma unroll
        for (int o = 1; o < 32; o <<= 1) {
            int t = __shfl_up(s, o, 64);
            if (lane >= o) s += t;
        }
        if (lane < SCAN_NB) spE[lane] = s - v;
    }

    int i0 = blockIdx.x * 2048 + threadIdx.x * 8;
    int v[8]; int s = 0;
    #pragma unroll
    for (int k = 0; k < 8; ++k) {
        int i = i0 + k;
        v[k] = (i < NN) ? deg[i] : 0;
        s += v[k];
    }
    int sc = s;
    #pragma unroll
    for (int o = 1; o < 64; o <<= 1) {
        int t = __shfl_up(sc, o, 64);
        if (lane >= o) sc += t;
    }
    if (lane == 63) ws[wid] = sc;
    __syncthreads();
    int woff = spE[blockIdx.x];
    for (int w = 0; w < wid; ++w) woff += ws[w];
    int excl = woff + sc - s;
    #pragma unroll
    for (int k = 0; k < 8; ++k) {
        int i = i0 + k;
        if (i < NN) { off[i] = excl; pos[i] = excl; }
        excl += v[k];
    }
    if (blockIdx.x == 0 && threadIdx.x == 0) off[NN] = ET;
}

// scatter, also recording dst per CSR slot (needed by edge_scores)
__global__ void edge_scatter2(const int* __restrict__ ei,
                              int* __restrict__ pos,
                              int* __restrict__ csr_src,
                              int* __restrict__ csr_dst)
{
    int t = blockIdx.x * blockDim.x + threadIdx.x;
    if (t >= ET) return;
    int src, dst;
    if (t < EE) { src = ei[t]; dst = ei[EE + t]; }
    else        { src = t - EE; dst = t - EE; }
    int p = atomicAdd(&pos[dst], 1);
    csr_src[p] = src;
    csr_dst[p] = dst;
}

// ---- edge-parallel softmax numerators: exf[e] = exp(lrelu(asrc+adst)) ------
__global__ __launch_bounds__(256) void edge_scores(
    const int* __restrict__ csr_src, const int* __restrict__ csr_dst,
    const float* __restrict__ asrc, const float* __restrict__ adst,
    float4* __restrict__ exf)
{
    int t = blockIdx.x * blockDim.x + threadIdx.x;
    if (t >= ET) return;
    int s = csr_src[t];
    int d = csr_dst[t];
    float4 a = *(const float4*)(asrc + (size_t)s * HH);
    float4 b = *(const float4*)(adst + (size_t)d * HH);
    float e0 = a.x + b.x; e0 = e0 > 0.f ? e0 : 0.2f * e0;
    float e1 = a.y + b.y; e1 = e1 > 0.f ? e1 : 0.2f * e1;
    float e2 = a.z + b.z; e2 = e2 > 0.f ? e2 : 0.2f * e2;
    float e3 = a.w + b.w; e3 = e3 > 0.f ? e3 : 0.2f * e3;
    exf[t] = make_float4(__expf(e0), __expf(e1), __expf(e2), __expf(e3));
}

// ---- fused aggregation + bias + ELU, precomputed edge scores ---------------
template<int C>
__global__ __launch_bounds__(256) void aggregate6(
    const unsigned short* __restrict__ h, const int* __restrict__ off,
    const int* __restrict__ csr_src, const float4* __restrict__ exf,
    const float* __restrict__ bias, unsigned short* __restrict__ outb)
{
    constexpr int HC = HH * C;          // 512 or 256
    constexpr int LPE = HC / 8;         // 64 or 32 lanes per edge-row
    constexpr int EPW = 64 / LPE;       // 1 or 2 edges in flight per wave
    constexpr int UNR = 8;              // edge groups per inner iteration
    __shared__ float exlds_all[4][64 * HH];
    int wave = threadIdx.x >> 6;
    int lane = threadIdx.x & 63;
    int n = blockIdx.x * 4 + wave;
    if (n >= NN) return;
    float* exlds = exlds_all[wave];
    int el  = (EPW == 1) ? 0 : (lane >> 5);
    int lel = (EPW == 1) ? lane : (lane & 31);
    int coff = lel * 8;
    int hl = coff / C;

    int start = off[n], end = off[n + 1];
    float dh0 = 0.f, dh1 = 0.f, dh2 = 0.f, dh3 = 0.f;
    float acc[8] = {0.f, 0.f, 0.f, 0.f, 0.f, 0.f, 0.f, 0.f};

    for (int cb = start; cb < end; cb += 64) {
        int eidx = cb + lane;
        bool valid = eidx < end;
        int s_lane = csr_src[valid ? eidx : end - 1];
        float4 xv = valid ? exf[eidx] : make_float4(0.f, 0.f, 0.f, 0.f);
        dh0 += xv.x; dh1 += xv.y; dh2 += xv.z; dh3 += xv.w;
        *(float4*)&exlds[lane * 4] = xv;
        // wave-synchronous LDS broadcast (compiler inserts lgkmcnt waits)

        int cnt = end - cb; if (cnt > 64) cnt = 64;
        int jmax = (cnt + UNR * EPW - 1) & ~(UNR * EPW - 1);  // padded: ex==0
        for (int jj = 0; jj < jmax; jj += UNR * EPW) {
            int sidx[UNR]; float xs[UNR]; ushort8 uv[UNR];
            #pragma unroll
            for (int u = 0; u < UNR; ++u) {
                int e_lo = jj + u * EPW;
                if (EPW == 1) {
                    sidx[u] = __builtin_amdgcn_readlane(s_lane, e_lo);
                } else {
                    int sa = __builtin_amdgcn_readlane(s_lane, e_lo);
                    int sb = __builtin_amdgcn_readlane(s_lane, e_lo + 1);
                    sidx[u] = el ? sb : sa;
                }
                uv[u] = *(const ushort8*)(h + (size_t)sidx[u] * HC + coff);
                xs[u] = exlds[(e_lo + el) * 4 + hl];
            }
            #pragma unroll
            for (int u = 0; u < UNR; ++u)
                #pragma unroll
                for (int c = 0; c < 8; ++c)
                    acc[c] += xs[u] * bf2f(uv[u][c]);
        }
    }

    #pragma unroll
    for (int o = 32; o > 0; o >>= 1) {
        dh0 += __shfl_xor(dh0, o, 64);
        dh1 += __shfl_xor(dh1, o, 64);
        dh2 += __shfl_xor(dh2, o, 64);
        dh3 += __shfl_xor(dh3, o, 64);
    }
    if (EPW == 2) {
        #pragma unroll
        for (int c = 0; c < 8; ++c)
            acc[c] += __shfl_xor(acc[c], 32, 64);
    }
    float d = (hl == 0) ? dh0 : (hl == 1) ? dh1 : (hl == 2) ? dh2 : dh3;
    float inv = 1.f / (d + 1e-16f);
    if (el == 0) {
        float4 b0 = *(const float4*)(bias + coff);
        float4 b1 = *(const float4*)(bias + coff + 4);
        float bb[8] = {b0.x, b0.y, b0.z, b0.w, b1.x, b1.y, b1.z, b1.w};
        unsigned int pk[4];
        #pragma unroll
        for (int c2 = 0; c2 < 4; ++c2) {
            float ua = acc[2 * c2]     * inv + bb[2 * c2];
            float ub = acc[2 * c2 + 1] * inv + bb[2 * c2 + 1];
            ua = ua > 0.f ? ua : expm1f(ua);
            ub = ub > 0.f ? ub : expm1f(ub);
            pk[c2] = (unsigned int)f2bf(ua) | ((unsigned int)f2bf(ub) << 16);
        }
        *(uint4*)(outb + (size_t)n * HC + coff) = make_uint4(pk[0], pk[1], pk[2], pk[3]);
    }
}

extern "C" void kernel_launch(void* const* d_in, const int* in_sizes, int n_in,
                              void* d_out, int out_size, void* d_ws, size_t ws_size,
                              hipStream_t stream) {
    const float* x      = (const float*)d_in[0];
    const int*   ei     = (const int*)d_in[1];
    const float* W1     = (const float*)d_in[2];
    const float* a_src1 = (const float*)d_in[3];
    const float* a_dst1 = (const float*)d_in[4];
    const float* b1     = (const float*)d_in[5];
    const float* W2     = (const float*)d_in[6];
    const float* a_src2 = (const float*)d_in[7];
    const float* a_dst2 = (const float*)d_in[8];
    const float* b2     = (const float*)d_in[9];
    const float* Wf     = (const float*)d_in[10];
    const float* bf     = (const float*)d_in[11];
    float* out = (float*)d_out;

    // workspace layout (all segments 16B-aligned).
    // asrc, adst, deg contiguous -> single memset covers them.
    char* p = (char*)d_ws;
    unsigned short* xb    = (unsigned short*)p; p += (size_t)NN * FIN * 2;
    unsigned short* h1b   = (unsigned short*)p; p += (size_t)NN * HH * CC1 * 2;
    unsigned short* out1b = (unsigned short*)p; p += (size_t)NN * HH * CC1 * 2;
    unsigned short* h2b   = (unsigned short*)p; p += (size_t)NN * HH * CC2 * 2;
    unsigned short* out2b = (unsigned short*)p; p += (size_t)NN * HH * CC2 * 2;
    unsigned short* W1t   = (unsigned short*)p; p += (size_t)FIN * HH * CC1 * 2;
    unsigned short* W2t   = (unsigned short*)p; p += (size_t)HH * CC1 * HH * CC2 * 2;
    unsigned short* Wft   = (unsigned short*)p; p += (size_t)64 * HH * CC2 * 2;
    float4* exf           = (float4*)p;         p += (size_t)ET * 16;
    float* asrc           = (float*)p;          p += (size_t)NN * HH * 4;
    float* adst           = (float*)p;          p += (size_t)NN * HH * 4;
    int* deg              = (int*)p;            p += (size_t)NN * 4;
    int* csr_off          = (int*)p;            p += (size_t)(NN + 1) * 4 + 12;
    int* csr_pos          = (int*)p;            p += (size_t)NN * 4;
    int* csr_src          = (int*)p;            p += (size_t)ET * 4;
    int* csr_dst          = (int*)p;            p += (size_t)ET * 4;
    int* partials         = (int*)p;            p += 64 * 4;

    // zero asrc+adst+deg in one shot (contiguous)
    hipMemsetAsync(asrc, 0, (size_t)(NN * HH * 2 + NN) * 4, stream);

    // fused prep: cast x, transpose W1/W2, pad-transpose Wf
    prep_fused<<<NB_CAST + NB_W1 + NB_W2 + NB_WF, 256, 0, stream>>>(
        x, xb, W1, W1t, W2, W2t, Wf, Wft);

    // CSR build
    edge_histogram<<<(ET + 255) / 256, 256, 0, stream>>>(ei, deg);
    scan_reduce<<<SCAN_NB, 256, 0, stream>>>(deg, partials);
    scan_apply<<<SCAN_NB, 256, 0, stream>>>(deg, partials, csr_off, csr_pos);
    edge_scatter2<<<(ET + 255) / 256, 256, 0, stream>>>(ei, csr_pos, csr_src, csr_dst);

    // layer 1: h1 = x @ W1 (+ fused attn scores; head = col>>7)
    gemm_bf16_v3<7><<<dim3((NN + 127) / 128, (HH * CC1) / 128), 256, 0, stream>>>(
        xb, W1t, h1b, a_src1, a_dst1, asrc, adst, NN, HH * CC1, FIN);
    edge_scores<<<(ET + 255) / 256, 256, 0, stream>>>(csr_src, csr_dst, asrc, adst, exf);
    aggregate6<CC1><<<(NN + 3) / 4, 256, 0, stream>>>(h1b, csr_off, csr_src, exf, b1, out1b);

    // re-zero asrc/adst for layer 2's atomics
    hipMemsetAsync(asrc, 0, (size_t)NN * HH * 2 * 4, stream);

    // layer 2: h2 = out1 @ W2 (+ fused attn scores; head = col>>6)
    gemm_bf16_v3<6><<<dim3((NN + 127) / 128, (HH * CC2) / 128), 256, 0, stream>>>(
        out1b, W2t, h2b, a_src2, a_dst2, asrc, adst, NN, HH * CC2, HH * CC1);
    edge_scores<<<(ET + 255) / 256, 256, 0, stream>>>(csr_src, csr_dst, asrc, adst, exf);
    aggregate6<CC2><<<(NN + 3) / 4, 256, 0, stream>>>(h2b, csr_off, csr_src, exf, b2, out2b);

    // final classifier: out = out2 @ Wf + bf  [50000,256]@[256,50] -> f32
    gemm_final<<<(NN + 127) / 128, 128, 0, stream>>>(out2b, Wft, bf, out, NN);
}

// Round 9
// 498.525 us; speedup vs baseline: 1.1084x; 1.1084x over previous
//
#include <hip/hip_runtime.h>
#include <hip/hip_fp16.h>
#include <cmath>

// Problem constants
#define NN 50000
#define EE 800000
#define ET 850000   // EE + NN self loops
#define HH 4
#define CC1 128
#define CC2 64
#define FIN 256
#define NCLS 50

typedef _Float16 half8_t __attribute__((ext_vector_type(8)));
typedef __attribute__((ext_vector_type(4))) float floatx4;

// async global->LDS, 16B per lane, wave-uniform LDS base + lane*16
typedef const __attribute__((address_space(1))) unsigned int* glds_gp_t;
typedef __attribute__((address_space(3))) unsigned int* glds_lp_t;
__device__ __forceinline__ void glds16(const void* g, void* l) {
    __builtin_amdgcn_global_load_lds((glds_gp_t)g, (glds_lp_t)l, 16, 0, 0);
}

// ------------- fused prep: cast x -> f16, transpose W1/W2, pad Wf -----------
#define NB_CAST 12500                  // NN*FIN/4 / 256
#define NB_W1   512                    // 256*512/256
#define NB_W2   512                    // 512*256/256
#define NB_WF   64                     // 256*64/256
__global__ __launch_bounds__(256) void prep_fused(
    const float* __restrict__ x, __half* __restrict__ xb,
    const float* __restrict__ W1, __half* __restrict__ W1t,
    const float* __restrict__ W2, __half* __restrict__ W2t,
    const float* __restrict__ Wf, __half* __restrict__ Wft)
{
    int b = blockIdx.x;
    if (b < NB_CAST) {
        int t = b * 256 + threadIdx.x;
        float4 v = *(const float4*)(x + 4 * (size_t)t);
        __half2 p[2];
        p[0] = __floats2half2_rn(v.x, v.y);
        p[1] = __floats2half2_rn(v.z, v.w);
        *(uint2*)(xb + 4 * (size_t)t) = *(uint2*)p;
    } else if (b < NB_CAST + NB_W1) {
        int t = (b - NB_CAST) * 256 + threadIdx.x;   // K=256, N=512
        int n = t >> 8, k = t & 255;
        W1t[t] = __float2half(W1[(size_t)k * 512 + n]);
    } else if (b < NB_CAST + NB_W1 + NB_W2) {
        int t = (b - NB_CAST - NB_W1) * 256 + threadIdx.x;  // K=512, N=256
        int n = t >> 9, k = t & 511;
        W2t[t] = __float2half(W2[(size_t)k * 256 + n]);
    } else {
        int t = (b - NB_CAST - NB_W1 - NB_W2) * 256 + threadIdx.x;  // K=256, Npad=64
        int n = t >> 8, k = t & 255;
        Wft[t] = (n < NCLS) ? __float2half(Wf[(size_t)k * NCLS + n]) : __float2half(0.f);
    }
}

// ------- f16 MFMA GEMM with global_load_lds staging (m97 structure) ---------
// C[M,N] = A[M,K] @ Bt[N,K]^T, output f16. N % 128 == 0, K % 32 == 0.
__global__ __launch_bounds__(256) void gemm_f16_v2(
    const __half* __restrict__ A,
    const __half* __restrict__ Bt,
    __half* __restrict__ C,
    int M, int N, int K)
{
    __shared__ __half As[128 * 32];
    __shared__ __half Bs[128 * 32];
    int tid = threadIdx.x, wave = tid >> 6, lane = tid & 63;
    int wm = (wave >> 1) * 64, wn = (wave & 1) * 64;
    int row0 = blockIdx.x * 128, col0 = blockIdx.y * 128;
    int lm = lane & 15, lq = lane >> 4, kq = lq * 8;
    floatx4 acc[4][4] = {};

    int srow = wave * 32 + (lane >> 2);
    int skk  = (lane & 3) * 8;
    int gra0 = row0 + srow;      if (gra0 >= M) gra0 = M - 1;
    int gra1 = row0 + srow + 16; if (gra1 >= M) gra1 = M - 1;
    const __half* ga0 = A + (size_t)gra0 * K + skk;
    const __half* ga1 = A + (size_t)gra1 * K + skk;
    const __half* gb0 = Bt + (size_t)(col0 + srow) * K + skk;
    const __half* gb1 = Bt + (size_t)(col0 + srow + 16) * K + skk;
    __half* la0 = &As[(wave * 32) * 32];
    __half* la1 = &As[(wave * 32 + 16) * 32];
    __half* lb0 = &Bs[(wave * 32) * 32];
    __half* lb1 = &Bs[(wave * 32 + 16) * 32];

    for (int k0 = 0; k0 < K; k0 += 32) {
        __syncthreads();
        glds16(ga0 + k0, la0);
        glds16(ga1 + k0, la1);
        glds16(gb0 + k0, lb0);
        glds16(gb1 + k0, lb1);
        __syncthreads();

        half8_t af[4], bfr[4];
        #pragma unroll
        for (int mt = 0; mt < 4; ++mt)
            af[mt] = *(const half8_t*)&As[(wm + mt * 16 + lm) * 32 + kq];
        #pragma unroll
        for (int nt = 0; nt < 4; ++nt)
            bfr[nt] = *(const half8_t*)&Bs[(wn + nt * 16 + lm) * 32 + kq];
        #pragma unroll
        for (int mt = 0; mt < 4; ++mt)
            #pragma unroll
            for (int nt = 0; nt < 4; ++nt)
                acc[mt][nt] = __builtin_amdgcn_mfma_f32_16x16x32_f16(
                    af[mt], bfr[nt], acc[mt][nt], 0, 0, 0);
    }

    // C/D layout: col = lane&15, row = (lane>>4)*4 + reg
    #pragma unroll
    for (int mt = 0; mt < 4; ++mt) {
        int rbase = row0 + wm + mt * 16 + lq * 4;
        #pragma unroll
        for (int nt = 0; nt < 4; ++nt) {
            int c = col0 + wn + nt * 16 + lm;
            #pragma unroll
            for (int r = 0; r < 4; ++r) {
                int gr = rbase + r;
                if (gr < M) C[(size_t)gr * N + c] = __float2half(acc[mt][nt][r]);
            }
        }
    }
}

// ---- final classifier: out[M,50] f32 = A[M,256]f16 @ Bt[64,256]^T + bias ---
__global__ __launch_bounds__(128) void gemm_final(
    const __half* __restrict__ A,
    const __half* __restrict__ Bt,   // [64,256], rows >= 50 are zero
    const float* __restrict__ bias,
    float* __restrict__ out, int M)
{
    __shared__ __half As[128 * 40];
    __shared__ __half Bs[64 * 40];
    int tid = threadIdx.x, wave = tid >> 6, lane = tid & 63;
    int row0 = blockIdx.x * 128;
    int lm = lane & 15, lq = lane >> 4, kq = lq * 8;
    floatx4 acc[4][4] = {};

    for (int k0 = 0; k0 < 256; k0 += 32) {
        int gr = row0 + tid; if (gr >= M) gr = M - 1;
        const __half* ap = A + (size_t)gr * 256 + k0;
        half8_t a0 = *(const half8_t*)ap;
        half8_t a1 = *(const half8_t*)(ap + 8);
        half8_t a2 = *(const half8_t*)(ap + 16);
        half8_t a3 = *(const half8_t*)(ap + 24);
        const __half* bp = Bt + (size_t)(tid >> 1) * 256 + k0 + (tid & 1) * 16;
        half8_t b0 = *(const half8_t*)bp;
        half8_t b1 = *(const half8_t*)(bp + 8);
        __syncthreads();
        *(half8_t*)&As[tid * 40 + 0]  = a0;
        *(half8_t*)&As[tid * 40 + 8]  = a1;
        *(half8_t*)&As[tid * 40 + 16] = a2;
        *(half8_t*)&As[tid * 40 + 24] = a3;
        *(half8_t*)&Bs[(tid >> 1) * 40 + (tid & 1) * 16]     = b0;
        *(half8_t*)&Bs[(tid >> 1) * 40 + (tid & 1) * 16 + 8] = b1;
        __syncthreads();

        half8_t af[4], bfr[4];
        #pragma unroll
        for (int mt = 0; mt < 4; ++mt)
            af[mt] = *(const half8_t*)&As[(wave * 64 + mt * 16 + lm) * 40 + kq];
        #pragma unroll
        for (int nt = 0; nt < 4; ++nt)
            bfr[nt] = *(const half8_t*)&Bs[(nt * 16 + lm) * 40 + kq];
        #pragma unroll
        for (int mt = 0; mt < 4; ++mt)
            #pragma unroll
            for (int nt = 0; nt < 4; ++nt)
                acc[mt][nt] = __builtin_amdgcn_mfma_f32_16x16x32_f16(
                    af[mt], bfr[nt], acc[mt][nt], 0, 0, 0);
    }

    #pragma unroll
    for (int mt = 0; mt < 4; ++mt) {
        int rbase = row0 + wave * 64 + mt * 16 + lq * 4;
        #pragma unroll
        for (int nt = 0; nt < 4; ++nt) {
            int c = nt * 16 + lm;
            if (c >= NCLS) continue;
            float bv = bias[c];
            #pragma unroll
            for (int r = 0; r < 4; ++r) {
                int gr = rbase + r;
                if (gr < M) out[(size_t)gr * NCLS + c] = acc[mt][nt][r] + bv;
            }
        }
    }
}

// ------------- per-node attention halves, vectorized (f16 h) ----------------
template<int C>
__global__ __launch_bounds__(256) void attn_scores2(
    const __half* __restrict__ h, const float* __restrict__ a_src,
    const float* __restrict__ a_dst, float* __restrict__ asrc,
    float* __restrict__ adst)
{
    constexpr int HC = HH * C;
    constexpr int CPL = HC / 64;   // 8 (C=128) or 4 (C=64)
    int wave = threadIdx.x >> 6;
    int lane = threadIdx.x & 63;
    int n = blockIdx.x * 4 + wave;
    if (n >= NN) return;
    int c0 = lane * CPL;
    int head = c0 / C;
    const __half* hp = h + (size_t)n * HC + c0;
    float hv[CPL];
    if (CPL == 8) {
        union { uint4 u; __half2 h2[4]; } U;
        U.u = *(const uint4*)hp;
        #pragma unroll
        for (int k = 0; k < 4; ++k) {
            float2 f = __half22float2(U.h2[k]);
            hv[2 * k] = f.x; hv[2 * k + 1] = f.y;
        }
    } else {
        union { uint2 u; __half2 h2[2]; } U;
        U.u = *(const uint2*)hp;
        #pragma unroll
        for (int k = 0; k < 2; ++k) {
            float2 f = __half22float2(U.h2[k]);
            hv[2 * k] = f.x; hv[2 * k + 1] = f.y;
        }
    }
    float s1 = 0.f, s2 = 0.f;
    #pragma unroll
    for (int c = 0; c < CPL; ++c) {
        s1 += hv[c] * a_src[c0 + c];
        s2 += hv[c] * a_dst[c0 + c];
    }
    #pragma unroll
    for (int o = 8; o > 0; o >>= 1) {
        s1 += __shfl_xor(s1, o, 64);
        s2 += __shfl_xor(s2, o, 64);
    }
    if ((lane & 15) == 0) {
        asrc[n * HH + head] = s1;
        adst[n * HH + head] = s2;
    }
}

// ---------------- CSR build: histogram, hierarchical scan, scatter ----------
__global__ void edge_histogram(const int* __restrict__ ei, int* __restrict__ deg)
{
    int t = blockIdx.x * blockDim.x + threadIdx.x;
    if (t >= ET) return;
    int dst = (t < EE) ? ei[EE + t] : (t - EE);
    atomicAdd(&deg[dst], 1);
}

__global__ __launch_bounds__(256) void scan_reduce(
    const int* __restrict__ deg, int* __restrict__ partials)
{
    int i0 = blockIdx.x * 2048 + threadIdx.x * 8;
    int s = 0;
    #pragma unroll
    for (int k = 0; k < 8; ++k) { int i = i0 + k; s += (i < NN) ? deg[i] : 0; }
    #pragma unroll
    for (int o = 32; o > 0; o >>= 1) s += __shfl_xor(s, o, 64);
    __shared__ int ws[4];
    int lane = threadIdx.x & 63, wid = threadIdx.x >> 6;
    if (lane == 0) ws[wid] = s;
    __syncthreads();
    if (threadIdx.x == 0) partials[blockIdx.x] = ws[0] + ws[1] + ws[2] + ws[3];
}

#define SCAN_NB 25                      // ceil(50000/2048)
__global__ __launch_bounds__(256) void scan_apply(
    const int* __restrict__ deg, const int* __restrict__ partials,
    int* __restrict__ off, int* __restrict__ pos)
{
    __shared__ int spE[SCAN_NB];
    __shared__ int ws[4];
    int lane = threadIdx.x & 63, wid = threadIdx.x >> 6;
    if (wid == 0) {
        int v = (lane < SCAN_NB) ? partials[lane] : 0;
        int s = v;
        #pragma unroll
        for (int o = 1; o < 32; o <<= 1) {
            int t = __shfl_up(s, o, 64);
            if (lane >= o) s += t;
        }
        if (lane < SCAN_NB) spE[lane] = s - v;
    }

    int i0 = blockIdx.x * 2048 + threadIdx.x * 8;
    int v[8]; int s = 0;
    #pragma unroll
    for (int k = 0; k < 8; ++k) {
        int i = i0 + k;
        v[k] = (i < NN) ? deg[i] : 0;
        s += v[k];
    }
    int sc = s;
    #pragma unroll
    for (int o = 1; o < 64; o <<= 1) {
        int t = __shfl_up(sc, o, 64);
        if (lane >= o) sc += t;
    }
    if (lane == 63) ws[wid] = sc;
    __syncthreads();
    int woff = spE[blockIdx.x];
    for (int w = 0; w < wid; ++w) woff += ws[w];
    int excl = woff + sc - s;
    #pragma unroll
    for (int k = 0; k < 8; ++k) {
        int i = i0 + k;
        if (i < NN) { off[i] = excl; pos[i] = excl; }
        excl += v[k];
    }
    if (blockIdx.x == 0 && threadIdx.x == 0) off[NN] = ET;
}

__global__ void edge_scatter(const int* __restrict__ ei,
                             int* __restrict__ pos, int* __restrict__ csr_src)
{
    int t = blockIdx.x * blockDim.x + threadIdx.x;
    if (t >= ET) return;
    int src, dst;
    if (t < EE) { src = ei[t]; dst = ei[EE + t]; }
    else        { src = t - EE; dst = t - EE; }
    int p = atomicAdd(&pos[dst], 1);
    csr_src[p] = src;
}

// ---- fused edge-softmax + aggregation + bias + ELU, f16 packed math --------
// Wave w of a 256-thread block handles node blockIdx.x*4+w independently.
// Score phase: lane i -> exp-scores of chunk edge i (4 heads), packed to
// half2 (duplicated) in LDS. Agg phase: ds_read_b32 alpha + 4 v_pk_fma_f16.
template<int C>
__global__ __launch_bounds__(256) void aggregate7(
    const __half* __restrict__ h, const int* __restrict__ off,
    const int* __restrict__ csr_src, const float* __restrict__ asrc,
    const float* __restrict__ adst, const float* __restrict__ bias,
    __half* __restrict__ outb)
{
    constexpr int HC = HH * C;          // 512 or 256
    constexpr int LPE = HC / 8;         // 64 or 32 lanes per edge-row
    constexpr int EPW = 64 / LPE;       // 1 or 2 edges in flight per wave
    constexpr int UNR = 8;              // edges (per el-half) per inner iter
    __shared__ unsigned int exlds_all[4][64 * HH];   // half2 (dup) per edge,head
    int wave = threadIdx.x >> 6;
    int lane = threadIdx.x & 63;
    int n = blockIdx.x * 4 + wave;
    if (n >= NN) return;
    unsigned int* exlds = exlds_all[wave];
    int el  = (EPW == 1) ? 0 : (lane >> 5);
    int lel = (EPW == 1) ? lane : (lane & 31);
    int coff = lel * 8;
    int hl = coff / C;

    int start = off[n], end = off[n + 1];
    float4 advv = *(const float4*)(adst + (size_t)n * HH);
    float dh0 = 0.f, dh1 = 0.f, dh2 = 0.f, dh3 = 0.f;
    __half2 acc2[4] = {};

    for (int cb = start; cb < end; cb += 64) {
        int eidx = cb + lane;
        bool valid = eidx < end;
        int s_lane = csr_src[valid ? eidx : end - 1];
        float4 t = *(const float4*)(asrc + (size_t)s_lane * HH);
        float e0 = t.x + advv.x; e0 = e0 > 0.f ? e0 : 0.2f * e0;
        float e1 = t.y + advv.y; e1 = e1 > 0.f ? e1 : 0.2f * e1;
        float e2 = t.z + advv.z; e2 = e2 > 0.f ? e2 : 0.2f * e2;
        float e3 = t.w + advv.w; e3 = e3 > 0.f ? e3 : 0.2f * e3;
        float x0 = valid ? __expf(e0) : 0.f;
        float x1 = valid ? __expf(e1) : 0.f;
        float x2 = valid ? __expf(e2) : 0.f;
        float x3 = valid ? __expf(e3) : 0.f;
        dh0 += x0; dh1 += x1; dh2 += x2; dh3 += x3;
        __half2 xp[4];
        xp[0] = __float2half2_rn(x0);
        xp[1] = __float2half2_rn(x1);
        xp[2] = __float2half2_rn(x2);
        xp[3] = __float2half2_rn(x3);
        *(uint4*)&exlds[lane * 4] = *(uint4*)xp;
        // wave-synchronous LDS broadcast (compiler inserts lgkmcnt waits)

        int cnt = end - cb; if (cnt > 64) cnt = 64;
        int jmax = (cnt + UNR * EPW - 1) & ~(UNR * EPW - 1);  // padded: ex==0
        for (int jj = 0; jj < jmax; jj += UNR * EPW) {
            int sidx[UNR]; __half2 xs[UNR];
            union { uint4 u; __half2 h2[4]; } uv[UNR];
            #pragma unroll
            for (int u = 0; u < UNR; ++u) {
                int e_lo = jj + u * EPW;
                if (EPW == 1) {
                    sidx[u] = __builtin_amdgcn_readlane(s_lane, e_lo);
                } else {
                    int sa = __builtin_amdgcn_readlane(s_lane, e_lo);
                    int sb = __builtin_amdgcn_readlane(s_lane, e_lo + 1);
                    sidx[u] = el ? sb : sa;
                }
                uv[u].u = *(const uint4*)(h + (size_t)sidx[u] * HC + coff);
                xs[u] = *(__half2*)&exlds[(e_lo + el) * 4 + hl];
            }
            #pragma unroll
            for (int u = 0; u < UNR; ++u)
                #pragma unroll
                for (int k = 0; k < 4; ++k)
                    acc2[k] = __hfma2(xs[u], uv[u].h2[k], acc2[k]);
        }
    }

    #pragma unroll
    for (int o = 32; o > 0; o >>= 1) {
        dh0 += __shfl_xor(dh0, o, 64);
        dh1 += __shfl_xor(dh1, o, 64);
        dh2 += __shfl_xor(dh2, o, 64);
        dh3 += __shfl_xor(dh3, o, 64);
    }
    float accf[8];
    #pragma unroll
    for (int k = 0; k < 4; ++k) {
        float2 f = __half22float2(acc2[k]);
        accf[2 * k] = f.x; accf[2 * k + 1] = f.y;
    }
    if (EPW == 2) {
        #pragma unroll
        for (int c = 0; c < 8; ++c)
            accf[c] += __shfl_xor(accf[c], 32, 64);
    }
    float d = (hl == 0) ? dh0 : (hl == 1) ? dh1 : (hl == 2) ? dh2 : dh3;
    float inv = 1.f / (d + 1e-16f);
    if (el == 0) {
        float4 b0 = *(const float4*)(bias + coff);
        float4 b1 = *(const float4*)(bias + coff + 4);
        float bb[8] = {b0.x, b0.y, b0.z, b0.w, b1.x, b1.y, b1.z, b1.w};
        __half2 pk[4];
        #pragma unroll
        for (int c2 = 0; c2 < 4; ++c2) {
            float ua = accf[2 * c2]     * inv + bb[2 * c2];
            float ub = accf[2 * c2 + 1] * inv + bb[2 * c2 + 1];
            ua = ua > 0.f ? ua : expm1f(ua);
            ub = ub > 0.f ? ub : expm1f(ub);
            pk[c2] = __floats2half2_rn(ua, ub);
        }
        *(uint4*)(outb + (size_t)n * HC + coff) = *(uint4*)pk;
    }
}

extern "C" void kernel_launch(void* const* d_in, const int* in_sizes, int n_in,
                              void* d_out, int out_size, void* d_ws, size_t ws_size,
                              hipStream_t stream) {
    const float* x      = (const float*)d_in[0];
    const int*   ei     = (const int*)d_in[1];
    const float* W1     = (const float*)d_in[2];
    const float* a_src1 = (const float*)d_in[3];
    const float* a_dst1 = (const float*)d_in[4];
    const float* b1     = (const float*)d_in[5];
    const float* W2     = (const float*)d_in[6];
    const float* a_src2 = (const float*)d_in[7];
    const float* a_dst2 = (const float*)d_in[8];
    const float* b2     = (const float*)d_in[9];
    const float* Wf     = (const float*)d_in[10];
    const float* bf     = (const float*)d_in[11];
    float* out = (float*)d_out;

    // workspace layout (all segments 16B-aligned)
    char* p = (char*)d_ws;
    __half* xb    = (__half*)p; p += (size_t)NN * FIN * 2;
    __half* h1b   = (__half*)p; p += (size_t)NN * HH * CC1 * 2;
    __half* out1b = (__half*)p; p += (size_t)NN * HH * CC1 * 2;
    __half* h2b   = (__half*)p; p += (size_t)NN * HH * CC2 * 2;
    __half* out2b = (__half*)p; p += (size_t)NN * HH * CC2 * 2;
    __half* W1t   = (__half*)p; p += (size_t)FIN * HH * CC1 * 2;
    __half* W2t   = (__half*)p; p += (size_t)HH * CC1 * HH * CC2 * 2;
    __half* Wft   = (__half*)p; p += (size_t)64 * HH * CC2 * 2;
    float* asrc   = (float*)p;  p += (size_t)NN * HH * 4;
    float* adst   = (float*)p;  p += (size_t)NN * HH * 4;
    int* deg      = (int*)p;    p += (size_t)NN * 4;
    int* csr_off  = (int*)p;    p += (size_t)(NN + 1) * 4 + 12;
    int* csr_pos  = (int*)p;    p += (size_t)NN * 4;
    int* csr_src  = (int*)p;    p += (size_t)ET * 4;
    int* partials = (int*)p;    p += 64 * 4;

    hipMemsetAsync(deg, 0, NN * sizeof(int), stream);

    // fused prep: cast x, transpose W1/W2, pad-transpose Wf
    prep_fused<<<NB_CAST + NB_W1 + NB_W2 + NB_WF, 256, 0, stream>>>(
        x, xb, W1, W1t, W2, W2t, Wf, Wft);

    // CSR build
    edge_histogram<<<(ET + 255) / 256, 256, 0, stream>>>(ei, deg);
    scan_reduce<<<SCAN_NB, 256, 0, stream>>>(deg, partials);
    scan_apply<<<SCAN_NB, 256, 0, stream>>>(deg, partials, csr_off, csr_pos);
    edge_scatter<<<(ET + 255) / 256, 256, 0, stream>>>(ei, csr_pos, csr_src);

    // layer 1: h1 = x @ W1  [50000,256]@[256,512] -> f16
    gemm_f16_v2<<<dim3((NN + 127) / 128, (HH * CC1) / 128), 256, 0, stream>>>(
        xb, W1t, h1b, NN, HH * CC1, FIN);
    attn_scores2<CC1><<<(NN + 3) / 4, 256, 0, stream>>>(h1b, a_src1, a_dst1, asrc, adst);
    aggregate7<CC1><<<(NN + 3) / 4, 256, 0, stream>>>(h1b, csr_off, csr_src, asrc, adst, b1, out1b);

    // layer 2: h2 = out1 @ W2  [50000,512]@[512,256] -> f16
    gemm_f16_v2<<<dim3((NN + 127) / 128, (HH * CC2) / 128), 256, 0, stream>>>(
        out1b, W2t, h2b, NN, HH * CC2, HH * CC1);
    attn_scores2<CC2><<<(NN + 3) / 4, 256, 0, stream>>>(h2b, a_src2, a_dst2, asrc, adst);
    aggregate7<CC2><<<(NN + 3) / 4, 256, 0, stream>>>(h2b, csr_off, csr_src, asrc, adst, b2, out2b);

    // final classifier: out = out2 @ Wf + bf  [50000,256]@[256,50] -> f32
    gemm_final<<<(NN + 127) / 128, 128, 0, stream>>>(out2b, Wft, bf, out, NN);
}